// Round 3
// baseline (208.503 us; speedup 1.0000x reference)
//
#include <hip/hip_runtime.h>
#include <math.h>

#define BS 8
#define P 8192
#define G 16
#define DIM 512

#define BLOCK 256
#define WAVES 4                 // waves per block
#define RPG 2                   // rows per 8-lane group
#define ROWS_PER_WAVE (8 * RPG)                 // 16
#define ROWS_PER_BLOCK (WAVES * ROWS_PER_WAVE) // 64
#define BLOCKS_PER_BATCH (P / ROWS_PER_BLOCK)  // 128
#define KSTEPS (DIM / 32)       // 16: per step a group covers 32 columns

__device__ __forceinline__ float smooth_l1(float d) {
    float a = fabsf(d);
    return a < 1.0f ? 0.5f * d * d : a - 0.5f;
}

__global__ __launch_bounds__(BLOCK, 4)
void det_main(const float* __restrict__ v,
              const float* __restrict__ gt,
              const float* __restrict__ rois,
              const float* __restrict__ labels,
              const float* __restrict__ pre_score,
              const float* __restrict__ cls_w,
              const float* __restrict__ cls_b,
              const float* __restrict__ reg_w,
              const float* __restrict__ reg_b,
              float* __restrict__ partials)   // [BS][3]: cnum, cden, l1
{
    const int tid  = threadIdx.x;
    const int lane = tid & 63;
    const int wave = tid >> 6;
    const int l    = lane & 7;   // lane within group
    const int grp  = lane >> 3;  // group within wave (0..7)
    const int b    = blockIdx.x / BLOCKS_PER_BATCH;
    const int blk  = blockIdx.x % BLOCKS_PER_BATCH;
    const int p0   = blk * ROWS_PER_BLOCK + wave * ROWS_PER_WAVE + grp * RPG;

    __shared__ float s_w[8 * DIM];   // 16 KB: c=0..3 cls, c=4..7 reg
    __shared__ float s_gt[G * 4];
    __shared__ int   s_lab;
    __shared__ float s_red[WAVES][3];

    // ---- stage weights into LDS (flat float4 copy)
    {
        const float4* cw = (const float4*)cls_w;   // 512 float4
        const float4* rw = (const float4*)reg_w;   // 512 float4
        float4* sw = (float4*)s_w;
        #pragma unroll
        for (int i = 0; i < 2; ++i) sw[i * BLOCK + tid]       = cw[i * BLOCK + tid];
        #pragma unroll
        for (int i = 0; i < 2; ++i) sw[512 + i * BLOCK + tid] = rw[i * BLOCK + tid];
    }
    if (tid < G * 4) s_gt[tid] = gt[b * G * 4 + tid];
    if (tid == 0) {
        const float* lb = labels + b * 4;
        int li = 0; float lm = lb[0];
        #pragma unroll
        for (int i = 1; i < 4; ++i) if (lb[i] > lm) { lm = lb[i]; li = i; }
        s_lab = li;
    }
    __syncthreads();
    const int lab = s_lab;

    // ---- hoisted epilogue loads (latency hides under GEMV)
    float4 rbox = make_float4(0.f, 0.f, 0.f, 1.f);
    float ps = 0.0f;
    if (l < RPG) {
        const int p = p0 + l;
        rbox = *(const float4*)(rois + ((size_t)b * P + p) * 4);
        ps   = pre_score[((size_t)b * P + p) * 4 + lab];
    }

    const float cb0 = cls_b[0], cb1 = cls_b[1], cb2 = cls_b[2], cb3 = cls_b[3];
    const float rb0 = reg_b[0], rb1 = reg_b[1], rb2 = reg_b[2], rb3 = reg_b[3];

    // ---- GEMV: acc[c][r] = partial dot of row (p0+r) with matrix c
    float acc[8][RPG];
    #pragma unroll
    for (int c = 0; c < 8; ++c)
        #pragma unroll
        for (int r = 0; r < RPG; ++r) acc[c][r] = 0.0f;

    const float* vb = v + ((size_t)b * P + p0) * DIM + l * 4;

    // 2-deep prefetch, fully static (no runtime-indexed register arrays)
    float4 nvA[RPG], nvB[RPG];
    #pragma unroll
    for (int r = 0; r < RPG; ++r) nvA[r] = *(const float4*)(vb + r * DIM);
    #pragma unroll
    for (int r = 0; r < RPG; ++r) nvB[r] = *(const float4*)(vb + r * DIM + 32);

    #pragma unroll
    for (int k = 0; k < KSTEPS; k += 2) {
        // step k (data in nvA)
        {
            float4 vv[RPG];
            #pragma unroll
            for (int r = 0; r < RPG; ++r) vv[r] = nvA[r];
            if (k + 2 < KSTEPS) {
                #pragma unroll
                for (int r = 0; r < RPG; ++r)
                    nvA[r] = *(const float4*)(vb + r * DIM + (k + 2) * 32);
            }
            float4 wv[8];
            #pragma unroll
            for (int c = 0; c < 8; ++c)
                wv[c] = *(const float4*)&s_w[c * DIM + l * 4 + k * 32];
            #pragma unroll
            for (int c = 0; c < 8; ++c)
                #pragma unroll
                for (int r = 0; r < RPG; ++r)
                    acc[c][r] += wv[c].x * vv[r].x + wv[c].y * vv[r].y
                               + wv[c].z * vv[r].z + wv[c].w * vv[r].w;
        }
        // step k+1 (data in nvB)
        {
            float4 vv[RPG];
            #pragma unroll
            for (int r = 0; r < RPG; ++r) vv[r] = nvB[r];
            if (k + 3 < KSTEPS) {
                #pragma unroll
                for (int r = 0; r < RPG; ++r)
                    nvB[r] = *(const float4*)(vb + r * DIM + (k + 3) * 32);
            }
            float4 wv[8];
            #pragma unroll
            for (int c = 0; c < 8; ++c)
                wv[c] = *(const float4*)&s_w[c * DIM + l * 4 + (k + 1) * 32];
            #pragma unroll
            for (int c = 0; c < 8; ++c)
                #pragma unroll
                for (int r = 0; r < RPG; ++r)
                    acc[c][r] += wv[c].x * vv[r].x + wv[c].y * vv[r].y
                               + wv[c].z * vv[r].z + wv[c].w * vv[r].w;
        }
    }

    // ---- reduce across the 8 lanes of each group (3 butterfly steps)
    #pragma unroll
    for (int c = 0; c < 8; ++c)
        #pragma unroll
        for (int r = 0; r < RPG; ++r) {
            float x = acc[c][r];
            x += __shfl_xor(x, 1);
            x += __shfl_xor(x, 2);
            x += __shfl_xor(x, 4);
            acc[c][r] = x;
        }

    // ---- epilogue: lane l (<RPG) of each group handles row p0+l
    float acc_cnum = 0.0f, acc_cden = 0.0f, acc_l1 = 0.0f;
    if (l < RPG) {
        float d[8];
        #pragma unroll
        for (int r = 0; r < RPG; ++r)
            if (l == r) {
                #pragma unroll
                for (int c = 0; c < 8; ++c) d[c] = acc[c][r];
            }
        const float area_r = (rbox.z - rbox.x) * (rbox.w - rbox.y);

        float biou = -1.0f; int bidx = 0;
        #pragma unroll
        for (int gi = 0; gi < G; ++gi) {
            float g0 = s_gt[gi * 4 + 0], g1 = s_gt[gi * 4 + 1];
            float g2 = s_gt[gi * 4 + 2], g3 = s_gt[gi * 4 + 3];
            float ltx = fmaxf(g0, rbox.x), lty = fmaxf(g1, rbox.y);
            float rbx = fminf(g2, rbox.z), rby = fminf(g3, rbox.w);
            float wx = fmaxf(rbx - ltx, 0.0f), wy = fmaxf(rby - lty, 0.0f);
            float inter = wx * wy;
            float ag = (g2 - g0) * (g3 - g1);
            float iou = inter / (ag + area_r - inter);
            if (iou > biou) { biou = iou; bidx = gi; }
        }
        const float mask = biou > 0.5f ? 1.0f : 0.0f;

        // cross-entropy on clipped logits
        float c0 = fminf(fmaxf(d[0] + cb0, 1e-7f), 0.99999994f);
        float c1 = fminf(fmaxf(d[1] + cb1, 1e-7f), 0.99999994f);
        float c2 = fminf(fmaxf(d[2] + cb2, 1e-7f), 0.99999994f);
        float c3 = fminf(fmaxf(d[3] + cb3, 1e-7f), 0.99999994f);
        float m  = fmaxf(fmaxf(c0, c1), fmaxf(c2, c3));
        float s  = expf(c0 - m) + expf(c1 - m) + expf(c2 - m) + expf(c3 - m);
        float lse = m + logf(s);
        float csel = lab == 0 ? c0 : (lab == 1 ? c1 : (lab == 2 ? c2 : c3));
        float ce = lse - csel;

        acc_cnum = ce * ps * mask;
        acc_cden = mask;

        // regression loss vs best-GT targets
        float bg0 = s_gt[bidx * 4 + 0], bg1 = s_gt[bidx * 4 + 1];
        float bg2 = s_gt[bidx * 4 + 2], bg3 = s_gt[bidx * 4 + 3];
        float gx = (bg2 + bg0) * 0.5f, gy = (bg3 + bg1) * 0.5f;
        float gw = (bg2 - bg0) * 0.5f, gh = (bg3 - bg1) * 0.5f;
        float rx = (rbox.z + rbox.x) * 0.5f, ry = (rbox.w + rbox.y) * 0.5f;
        float rw_ = (rbox.z - rbox.x) * 0.5f, rh = (rbox.w - rbox.y) * 0.5f;
        float tx = (gx - rx) / (rw_ + 1e-8f);
        float ty = (gy - ry) / (rh + 1e-8f);
        float tw = logf(gw / (rw_ + 1e-8f));
        float th = logf(gh / (rh + 1e-8f));
        float l1v = smooth_l1(d[4] + rb0 - tx) + smooth_l1(d[5] + rb1 - ty)
                  + smooth_l1(d[6] + rb2 - tw) + smooth_l1(d[7] + rb3 - th);
        acc_l1 = l1v * mask * ps;
    }

    // ---- full-wave butterfly sum of the three partials
    #pragma unroll
    for (int off = 32; off > 0; off >>= 1) {
        acc_cnum += __shfl_xor(acc_cnum, off);
        acc_cden += __shfl_xor(acc_cden, off);
        acc_l1   += __shfl_xor(acc_l1,   off);
    }
    if (lane == 0) {
        s_red[wave][0] = acc_cnum;
        s_red[wave][1] = acc_cden;
        s_red[wave][2] = acc_l1;
    }
    __syncthreads();
    if (tid == 0) {
        float a = 0.0f, bb = 0.0f, cc = 0.0f;
        #pragma unroll
        for (int wv = 0; wv < WAVES; ++wv) {
            a  += s_red[wv][0];
            bb += s_red[wv][1];
            cc += s_red[wv][2];
        }
        atomicAdd(&partials[b * 3 + 0], a);
        atomicAdd(&partials[b * 3 + 1], bb);
        atomicAdd(&partials[b * 3 + 2], cc);
    }
}

__global__ void det_final(const float* __restrict__ partials, float* __restrict__ out)
{
    if (threadIdx.x == 0 && blockIdx.x == 0) {
        float cl = 0.0f, l1 = 0.0f;
        #pragma unroll
        for (int b = 0; b < BS; ++b) {
            cl += partials[b * 3 + 0] / (partials[b * 3 + 1] + 1e-7f);
            l1 += partials[b * 3 + 2];
        }
        out[0] = cl / ((float)BS + 1e-7f) + l1 / (float)(BS * P);
    }
}

extern "C" void kernel_launch(void* const* d_in, const int* in_sizes, int n_in,
                              void* d_out, int out_size, void* d_ws, size_t ws_size,
                              hipStream_t stream) {
    const float* v         = (const float*)d_in[0];
    const float* gt        = (const float*)d_in[1];
    const float* rois      = (const float*)d_in[2];
    const float* labels    = (const float*)d_in[3];
    const float* pre_score = (const float*)d_in[4];
    const float* cls_w     = (const float*)d_in[5];
    const float* cls_b     = (const float*)d_in[6];
    const float* reg_w     = (const float*)d_in[7];
    const float* reg_b     = (const float*)d_in[8];
    float* partials = (float*)d_ws;
    float* out      = (float*)d_out;

    hipMemsetAsync(d_ws, 0, BS * 3 * sizeof(float), stream);
    det_main<<<(BS * P) / ROWS_PER_BLOCK, BLOCK, 0, stream>>>(
        v, gt, rois, labels, pre_score, cls_w, cls_b, reg_w, reg_b, partials);
    det_final<<<1, 64, 0, stream>>>(partials, out);
}

// Round 4
// 89.725 us; speedup vs baseline: 2.3238x; 2.3238x over previous
//
#include <hip/hip_runtime.h>
#include <math.h>

#define BS 8
#define P 8192
#define G 16
#define DIM 512

#define BLOCK 256
#define WAVES 4                 // waves per block
#define RPG 2                   // rows per 8-lane group
#define ROWS_PER_WAVE (8 * RPG)                 // 16
#define ROWS_PER_BLOCK (WAVES * ROWS_PER_WAVE) // 64
#define BLOCKS_PER_BATCH (P / ROWS_PER_BLOCK)  // 128
#define KSTEPS (DIM / 32)       // 16: per step a group covers 32 columns

__device__ __forceinline__ float smooth_l1(float d) {
    float a = fabsf(d);
    return a < 1.0f ? 0.5f * d * d : a - 0.5f;
}

__global__ __launch_bounds__(BLOCK, 4)
void det_main(const float* __restrict__ v,
              const float* __restrict__ gt,
              const float* __restrict__ rois,
              const float* __restrict__ labels,
              const float* __restrict__ pre_score,
              const float* __restrict__ cls_w,
              const float* __restrict__ cls_b,
              const float* __restrict__ reg_w,
              const float* __restrict__ reg_b,
              float* __restrict__ partials)   // [BS][3]: cnum, cden, l1
{
    const int tid  = threadIdx.x;
    const int lane = tid & 63;
    const int wave = tid >> 6;
    const int l    = lane & 7;   // lane within group
    const int grp  = lane >> 3;  // group within wave (0..7)
    const int b    = blockIdx.x / BLOCKS_PER_BATCH;
    const int blk  = blockIdx.x % BLOCKS_PER_BATCH;
    const int p0   = blk * ROWS_PER_BLOCK + wave * ROWS_PER_WAVE + grp * RPG;

    __shared__ float s_w[8 * DIM];   // 16 KB: c=0..3 cls, c=4..7 reg
    __shared__ float s_gt[G * 4];
    __shared__ int   s_lab;
    __shared__ float s_red[WAVES][3];

    // ---- stage weights into LDS (flat float4 copy)
    {
        const float4* cw = (const float4*)cls_w;   // 512 float4
        const float4* rw = (const float4*)reg_w;   // 512 float4
        float4* sw = (float4*)s_w;
        #pragma unroll
        for (int i = 0; i < 2; ++i) sw[i * BLOCK + tid]       = cw[i * BLOCK + tid];
        #pragma unroll
        for (int i = 0; i < 2; ++i) sw[512 + i * BLOCK + tid] = rw[i * BLOCK + tid];
    }
    if (tid < G * 4) s_gt[tid] = gt[b * G * 4 + tid];
    if (tid == 0) {
        const float* lb = labels + b * 4;
        int li = 0; float lm = lb[0];
        #pragma unroll
        for (int i = 1; i < 4; ++i) if (lb[i] > lm) { lm = lb[i]; li = i; }
        s_lab = li;
    }
    __syncthreads();
    const int lab = s_lab;

    // ---- hoisted epilogue loads (latency hides under GEMV)
    float4 rbox = make_float4(0.f, 0.f, 0.f, 1.f);
    float ps = 0.0f;
    if (l < RPG) {
        const int p = p0 + l;
        rbox = *(const float4*)(rois + ((size_t)b * P + p) * 4);
        ps   = pre_score[((size_t)b * P + p) * 4 + lab];
    }

    const float cb0 = cls_b[0], cb1 = cls_b[1], cb2 = cls_b[2], cb3 = cls_b[3];
    const float rb0 = reg_b[0], rb1 = reg_b[1], rb2 = reg_b[2], rb3 = reg_b[3];

    // ---- GEMV: acc[c][r] = partial dot of row (p0+r) with matrix c
    float acc[8][RPG];
    #pragma unroll
    for (int c = 0; c < 8; ++c)
        #pragma unroll
        for (int r = 0; r < RPG; ++r) acc[c][r] = 0.0f;

    const float* vb = v + ((size_t)b * P + p0) * DIM + l * 4;

    // 1-deep prefetch, partial unroll (keeps live ranges tight -> no spill)
    float4 nv[RPG];
    #pragma unroll
    for (int r = 0; r < RPG; ++r) nv[r] = *(const float4*)(vb + r * DIM);

    #pragma unroll 4
    for (int k = 0; k < KSTEPS; ++k) {
        float4 vv[RPG];
        #pragma unroll
        for (int r = 0; r < RPG; ++r) vv[r] = nv[r];
        if (k + 1 < KSTEPS) {
            #pragma unroll
            for (int r = 0; r < RPG; ++r)
                nv[r] = *(const float4*)(vb + r * DIM + (k + 1) * 32);
        }
        float4 wv[8];
        #pragma unroll
        for (int c = 0; c < 8; ++c)
            wv[c] = *(const float4*)&s_w[c * DIM + l * 4 + k * 32];
        #pragma unroll
        for (int c = 0; c < 8; ++c)
            #pragma unroll
            for (int r = 0; r < RPG; ++r)
                acc[c][r] += wv[c].x * vv[r].x + wv[c].y * vv[r].y
                           + wv[c].z * vv[r].z + wv[c].w * vv[r].w;
    }

    // ---- reduce across the 8 lanes of each group (3 butterfly steps)
    #pragma unroll
    for (int c = 0; c < 8; ++c)
        #pragma unroll
        for (int r = 0; r < RPG; ++r) {
            float x = acc[c][r];
            x += __shfl_xor(x, 1);
            x += __shfl_xor(x, 2);
            x += __shfl_xor(x, 4);
            acc[c][r] = x;
        }

    // ---- epilogue: lane l (<RPG) of each group handles row p0+l
    float acc_cnum = 0.0f, acc_cden = 0.0f, acc_l1 = 0.0f;
    if (l < RPG) {
        float d[8];
        #pragma unroll
        for (int r = 0; r < RPG; ++r)
            if (l == r) {
                #pragma unroll
                for (int c = 0; c < 8; ++c) d[c] = acc[c][r];
            }
        const float area_r = (rbox.z - rbox.x) * (rbox.w - rbox.y);

        float biou = -1.0f; int bidx = 0;
        #pragma unroll
        for (int gi = 0; gi < G; ++gi) {
            float g0 = s_gt[gi * 4 + 0], g1 = s_gt[gi * 4 + 1];
            float g2 = s_gt[gi * 4 + 2], g3 = s_gt[gi * 4 + 3];
            float ltx = fmaxf(g0, rbox.x), lty = fmaxf(g1, rbox.y);
            float rbx = fminf(g2, rbox.z), rby = fminf(g3, rbox.w);
            float wx = fmaxf(rbx - ltx, 0.0f), wy = fmaxf(rby - lty, 0.0f);
            float inter = wx * wy;
            float ag = (g2 - g0) * (g3 - g1);
            float iou = inter / (ag + area_r - inter);
            if (iou > biou) { biou = iou; bidx = gi; }
        }
        const float mask = biou > 0.5f ? 1.0f : 0.0f;

        // cross-entropy on clipped logits
        float c0 = fminf(fmaxf(d[0] + cb0, 1e-7f), 0.99999994f);
        float c1 = fminf(fmaxf(d[1] + cb1, 1e-7f), 0.99999994f);
        float c2 = fminf(fmaxf(d[2] + cb2, 1e-7f), 0.99999994f);
        float c3 = fminf(fmaxf(d[3] + cb3, 1e-7f), 0.99999994f);
        float m  = fmaxf(fmaxf(c0, c1), fmaxf(c2, c3));
        float s  = expf(c0 - m) + expf(c1 - m) + expf(c2 - m) + expf(c3 - m);
        float lse = m + logf(s);
        float csel = lab == 0 ? c0 : (lab == 1 ? c1 : (lab == 2 ? c2 : c3));
        float ce = lse - csel;

        acc_cnum = ce * ps * mask;
        acc_cden = mask;

        // regression loss vs best-GT targets
        float bg0 = s_gt[bidx * 4 + 0], bg1 = s_gt[bidx * 4 + 1];
        float bg2 = s_gt[bidx * 4 + 2], bg3 = s_gt[bidx * 4 + 3];
        float gx = (bg2 + bg0) * 0.5f, gy = (bg3 + bg1) * 0.5f;
        float gw = (bg2 - bg0) * 0.5f, gh = (bg3 - bg1) * 0.5f;
        float rx = (rbox.z + rbox.x) * 0.5f, ry = (rbox.w + rbox.y) * 0.5f;
        float rw_ = (rbox.z - rbox.x) * 0.5f, rh = (rbox.w - rbox.y) * 0.5f;
        float tx = (gx - rx) / (rw_ + 1e-8f);
        float ty = (gy - ry) / (rh + 1e-8f);
        float tw = logf(gw / (rw_ + 1e-8f));
        float th = logf(gh / (rh + 1e-8f));
        float l1v = smooth_l1(d[4] + rb0 - tx) + smooth_l1(d[5] + rb1 - ty)
                  + smooth_l1(d[6] + rb2 - tw) + smooth_l1(d[7] + rb3 - th);
        acc_l1 = l1v * mask * ps;
    }

    // ---- full-wave butterfly sum of the three partials
    #pragma unroll
    for (int off = 32; off > 0; off >>= 1) {
        acc_cnum += __shfl_xor(acc_cnum, off);
        acc_cden += __shfl_xor(acc_cden, off);
        acc_l1   += __shfl_xor(acc_l1,   off);
    }
    if (lane == 0) {
        s_red[wave][0] = acc_cnum;
        s_red[wave][1] = acc_cden;
        s_red[wave][2] = acc_l1;
    }
    __syncthreads();
    if (tid == 0) {
        float a = 0.0f, bb = 0.0f, cc = 0.0f;
        #pragma unroll
        for (int wv = 0; wv < WAVES; ++wv) {
            a  += s_red[wv][0];
            bb += s_red[wv][1];
            cc += s_red[wv][2];
        }
        atomicAdd(&partials[b * 3 + 0], a);
        atomicAdd(&partials[b * 3 + 1], bb);
        atomicAdd(&partials[b * 3 + 2], cc);
    }
}

__global__ void det_final(const float* __restrict__ partials, float* __restrict__ out)
{
    if (threadIdx.x == 0 && blockIdx.x == 0) {
        float cl = 0.0f, l1 = 0.0f;
        #pragma unroll
        for (int b = 0; b < BS; ++b) {
            cl += partials[b * 3 + 0] / (partials[b * 3 + 1] + 1e-7f);
            l1 += partials[b * 3 + 2];
        }
        out[0] = cl / ((float)BS + 1e-7f) + l1 / (float)(BS * P);
    }
}

extern "C" void kernel_launch(void* const* d_in, const int* in_sizes, int n_in,
                              void* d_out, int out_size, void* d_ws, size_t ws_size,
                              hipStream_t stream) {
    const float* v         = (const float*)d_in[0];
    const float* gt        = (const float*)d_in[1];
    const float* rois      = (const float*)d_in[2];
    const float* labels    = (const float*)d_in[3];
    const float* pre_score = (const float*)d_in[4];
    const float* cls_w     = (const float*)d_in[5];
    const float* cls_b     = (const float*)d_in[6];
    const float* reg_w     = (const float*)d_in[7];
    const float* reg_b     = (const float*)d_in[8];
    float* partials = (float*)d_ws;
    float* out      = (float*)d_out;

    hipMemsetAsync(d_ws, 0, BS * 3 * sizeof(float), stream);
    det_main<<<(BS * P) / ROWS_PER_BLOCK, BLOCK, 0, stream>>>(
        v, gt, rois, labels, pre_score, cls_w, cls_b, reg_w, reg_b, partials);
    det_final<<<1, 64, 0, stream>>>(partials, out);
}

// Round 5
// 57.508 us; speedup vs baseline: 3.6256x; 1.5602x over previous
//
#include <hip/hip_runtime.h>
#include <math.h>

#define BS 8
#define P 8192
#define G 16
#define DIM 512

#define BLOCK 256
#define WAVES 4                 // waves per block
#define RPG 2                   // rows per 8-lane group
#define ROWS_PER_WAVE (8 * RPG)                 // 16
#define ROWS_PER_BLOCK (WAVES * ROWS_PER_WAVE) // 64
#define BLOCKS_PER_BATCH (P / ROWS_PER_BLOCK)  // 128
#define KSTEPS (DIM / 32)       // 16: per step a group covers 32 columns

__device__ __forceinline__ float smooth_l1(float d) {
    float a = fabsf(d);
    return a < 1.0f ? 0.5f * d * d : a - 0.5f;
}

// NOTE: min-waves/EU deliberately 2 (NOT 4): the ",4" bound made the compiler
// clamp to 64 VGPR and spill ~2KB/thread (125-421 MB of scratch HBM writes in
// rounds 3/4). Occupancy comes from the 1024-block grid instead.
__global__ __launch_bounds__(BLOCK, 2)
void det_main(const float* __restrict__ v,
              const float* __restrict__ gt,
              const float* __restrict__ rois,
              const float* __restrict__ labels,
              const float* __restrict__ pre_score,
              const float* __restrict__ cls_w,
              const float* __restrict__ cls_b,
              const float* __restrict__ reg_w,
              const float* __restrict__ reg_b,
              float* __restrict__ partials)   // [BS][3]: cnum, cden, l1
{
    const int tid  = threadIdx.x;
    const int lane = tid & 63;
    const int wave = tid >> 6;
    const int l    = lane & 7;   // lane within group
    const int grp  = lane >> 3;  // group within wave (0..7)
    const int b    = blockIdx.x / BLOCKS_PER_BATCH;
    const int blk  = blockIdx.x % BLOCKS_PER_BATCH;
    const int p0   = blk * ROWS_PER_BLOCK + wave * ROWS_PER_WAVE + grp * RPG;

    __shared__ float s_w[8 * DIM];   // 16 KB: c=0..3 cls, c=4..7 reg
    __shared__ float s_gt[G * 4];
    __shared__ int   s_lab;
    __shared__ float s_red[WAVES][3];

    // ---- stage weights into LDS (flat float4 copy)
    {
        const float4* cw = (const float4*)cls_w;   // 512 float4
        const float4* rw = (const float4*)reg_w;   // 512 float4
        float4* sw = (float4*)s_w;
        #pragma unroll
        for (int i = 0; i < 2; ++i) sw[i * BLOCK + tid]       = cw[i * BLOCK + tid];
        #pragma unroll
        for (int i = 0; i < 2; ++i) sw[512 + i * BLOCK + tid] = rw[i * BLOCK + tid];
    }
    if (tid < G * 4) s_gt[tid] = gt[b * G * 4 + tid];
    if (tid == 0) {
        const float* lb = labels + b * 4;
        int li = 0; float lm = lb[0];
        #pragma unroll
        for (int i = 1; i < 4; ++i) if (lb[i] > lm) { lm = lb[i]; li = i; }
        s_lab = li;
    }
    __syncthreads();
    const int lab = s_lab;

    // ---- hoisted epilogue loads (latency hides under GEMV)
    float4 rbox = make_float4(0.f, 0.f, 0.f, 1.f);
    float ps = 0.0f;
    if (l < RPG) {
        const int p = p0 + l;
        rbox = *(const float4*)(rois + ((size_t)b * P + p) * 4);
        ps   = pre_score[((size_t)b * P + p) * 4 + lab];
    }

    const float cb0 = cls_b[0], cb1 = cls_b[1], cb2 = cls_b[2], cb3 = cls_b[3];
    const float rb0 = reg_b[0], rb1 = reg_b[1], rb2 = reg_b[2], rb3 = reg_b[3];

    // ---- GEMV: acc[c][r] = partial dot of row (p0+r) with matrix c
    float acc[8][RPG];
    #pragma unroll
    for (int c = 0; c < 8; ++c)
        #pragma unroll
        for (int r = 0; r < RPG; ++r) acc[c][r] = 0.0f;

    const float* vb = v + ((size_t)b * P + p0) * DIM + l * 4;

    // 1-deep prefetch, partial unroll (keeps live ranges tight -> no spill)
    float4 nv[RPG];
    #pragma unroll
    for (int r = 0; r < RPG; ++r) nv[r] = *(const float4*)(vb + r * DIM);

    #pragma unroll 4
    for (int k = 0; k < KSTEPS; ++k) {
        float4 vv[RPG];
        #pragma unroll
        for (int r = 0; r < RPG; ++r) vv[r] = nv[r];
        if (k + 1 < KSTEPS) {
            #pragma unroll
            for (int r = 0; r < RPG; ++r)
                nv[r] = *(const float4*)(vb + r * DIM + (k + 1) * 32);
        }
        // two halves of 4 weight vectors each -> peak live wv regs halved
        #pragma unroll
        for (int h = 0; h < 2; ++h) {
            float4 wv[4];
            #pragma unroll
            for (int c = 0; c < 4; ++c)
                wv[c] = *(const float4*)&s_w[(h * 4 + c) * DIM + l * 4 + k * 32];
            #pragma unroll
            for (int c = 0; c < 4; ++c)
                #pragma unroll
                for (int r = 0; r < RPG; ++r)
                    acc[h * 4 + c][r] += wv[c].x * vv[r].x + wv[c].y * vv[r].y
                                       + wv[c].z * vv[r].z + wv[c].w * vv[r].w;
        }
    }

    // ---- reduce across the 8 lanes of each group (3 butterfly steps)
    #pragma unroll
    for (int c = 0; c < 8; ++c)
        #pragma unroll
        for (int r = 0; r < RPG; ++r) {
            float x = acc[c][r];
            x += __shfl_xor(x, 1);
            x += __shfl_xor(x, 2);
            x += __shfl_xor(x, 4);
            acc[c][r] = x;
        }

    // ---- epilogue: lane l (<RPG) of each group handles row p0+l
    float acc_cnum = 0.0f, acc_cden = 0.0f, acc_l1 = 0.0f;
    if (l < RPG) {
        float d[8];
        #pragma unroll
        for (int r = 0; r < RPG; ++r)
            if (l == r) {
                #pragma unroll
                for (int c = 0; c < 8; ++c) d[c] = acc[c][r];
            }
        const float area_r = (rbox.z - rbox.x) * (rbox.w - rbox.y);

        float biou = -1.0f; int bidx = 0;
        #pragma unroll
        for (int gi = 0; gi < G; ++gi) {
            float g0 = s_gt[gi * 4 + 0], g1 = s_gt[gi * 4 + 1];
            float g2 = s_gt[gi * 4 + 2], g3 = s_gt[gi * 4 + 3];
            float ltx = fmaxf(g0, rbox.x), lty = fmaxf(g1, rbox.y);
            float rbx = fminf(g2, rbox.z), rby = fminf(g3, rbox.w);
            float wx = fmaxf(rbx - ltx, 0.0f), wy = fmaxf(rby - lty, 0.0f);
            float inter = wx * wy;
            float ag = (g2 - g0) * (g3 - g1);
            float iou = inter / (ag + area_r - inter);
            if (iou > biou) { biou = iou; bidx = gi; }
        }
        const float mask = biou > 0.5f ? 1.0f : 0.0f;

        // cross-entropy on clipped logits
        float c0 = fminf(fmaxf(d[0] + cb0, 1e-7f), 0.99999994f);
        float c1 = fminf(fmaxf(d[1] + cb1, 1e-7f), 0.99999994f);
        float c2 = fminf(fmaxf(d[2] + cb2, 1e-7f), 0.99999994f);
        float c3 = fminf(fmaxf(d[3] + cb3, 1e-7f), 0.99999994f);
        float m  = fmaxf(fmaxf(c0, c1), fmaxf(c2, c3));
        float s  = expf(c0 - m) + expf(c1 - m) + expf(c2 - m) + expf(c3 - m);
        float lse = m + logf(s);
        float csel = lab == 0 ? c0 : (lab == 1 ? c1 : (lab == 2 ? c2 : c3));
        float ce = lse - csel;

        acc_cnum = ce * ps * mask;
        acc_cden = mask;

        // regression loss vs best-GT targets
        float bg0 = s_gt[bidx * 4 + 0], bg1 = s_gt[bidx * 4 + 1];
        float bg2 = s_gt[bidx * 4 + 2], bg3 = s_gt[bidx * 4 + 3];
        float gx = (bg2 + bg0) * 0.5f, gy = (bg3 + bg1) * 0.5f;
        float gw = (bg2 - bg0) * 0.5f, gh = (bg3 - bg1) * 0.5f;
        float rx = (rbox.z + rbox.x) * 0.5f, ry = (rbox.w + rbox.y) * 0.5f;
        float rw_ = (rbox.z - rbox.x) * 0.5f, rh = (rbox.w - rbox.y) * 0.5f;
        float tx = (gx - rx) / (rw_ + 1e-8f);
        float ty = (gy - ry) / (rh + 1e-8f);
        float tw = logf(gw / (rw_ + 1e-8f));
        float th = logf(gh / (rh + 1e-8f));
        float l1v = smooth_l1(d[4] + rb0 - tx) + smooth_l1(d[5] + rb1 - ty)
                  + smooth_l1(d[6] + rb2 - tw) + smooth_l1(d[7] + rb3 - th);
        acc_l1 = l1v * mask * ps;
    }

    // ---- full-wave butterfly sum of the three partials
    #pragma unroll
    for (int off = 32; off > 0; off >>= 1) {
        acc_cnum += __shfl_xor(acc_cnum, off);
        acc_cden += __shfl_xor(acc_cden, off);
        acc_l1   += __shfl_xor(acc_l1,   off);
    }
    if (lane == 0) {
        s_red[wave][0] = acc_cnum;
        s_red[wave][1] = acc_cden;
        s_red[wave][2] = acc_l1;
    }
    __syncthreads();
    if (tid == 0) {
        float a = 0.0f, bb = 0.0f, cc = 0.0f;
        #pragma unroll
        for (int wv = 0; wv < WAVES; ++wv) {
            a  += s_red[wv][0];
            bb += s_red[wv][1];
            cc += s_red[wv][2];
        }
        atomicAdd(&partials[b * 3 + 0], a);
        atomicAdd(&partials[b * 3 + 1], bb);
        atomicAdd(&partials[b * 3 + 2], cc);
    }
}

__global__ void det_final(const float* __restrict__ partials, float* __restrict__ out)
{
    if (threadIdx.x == 0 && blockIdx.x == 0) {
        float cl = 0.0f, l1 = 0.0f;
        #pragma unroll
        for (int b = 0; b < BS; ++b) {
            cl += partials[b * 3 + 0] / (partials[b * 3 + 1] + 1e-7f);
            l1 += partials[b * 3 + 2];
        }
        out[0] = cl / ((float)BS + 1e-7f) + l1 / (float)(BS * P);
    }
}

extern "C" void kernel_launch(void* const* d_in, const int* in_sizes, int n_in,
                              void* d_out, int out_size, void* d_ws, size_t ws_size,
                              hipStream_t stream) {
    const float* v         = (const float*)d_in[0];
    const float* gt        = (const float*)d_in[1];
    const float* rois      = (const float*)d_in[2];
    const float* labels    = (const float*)d_in[3];
    const float* pre_score = (const float*)d_in[4];
    const float* cls_w     = (const float*)d_in[5];
    const float* cls_b     = (const float*)d_in[6];
    const float* reg_w     = (const float*)d_in[7];
    const float* reg_b     = (const float*)d_in[8];
    float* partials = (float*)d_ws;
    float* out      = (float*)d_out;

    hipMemsetAsync(d_ws, 0, BS * 3 * sizeof(float), stream);
    det_main<<<(BS * P) / ROWS_PER_BLOCK, BLOCK, 0, stream>>>(
        v, gt, rois, labels, pre_score, cls_w, cls_b, reg_w, reg_b, partials);
    det_final<<<1, 64, 0, stream>>>(partials, out);
}

// Round 6
// 49.993 us; speedup vs baseline: 4.1707x; 1.1503x over previous
//
#include <hip/hip_runtime.h>
#include <math.h>

#define BS 8
#define P 8192
#define G 16
#define DIM 512

#define BLOCK 256
#define WAVES 4                 // waves per block
#define RPG 4                   // rows per 8-lane group
#define ROWS_PER_WAVE (8 * RPG)                 // 32
#define ROWS_PER_BLOCK (WAVES * ROWS_PER_WAVE) // 128
#define BLOCKS_PER_BATCH (P / ROWS_PER_BLOCK)  // 64  -> grid 512
#define KSTEPS (DIM / 32)       // 16: per step a group covers 32 columns

__device__ __forceinline__ float smooth_l1(float d) {
    float a = fabsf(d);
    return a < 1.0f ? 0.5f * d * d : a - 0.5f;
}

// launch_bounds min-waves/EU = 1 (VGPR cap 512): occupancy is fixed by the
// 512-block grid (2 blocks/CU = 2 waves/SIMD), so any VGPR count <= 256 is
// free. The ",4" bound (cap 64) caused 125-421 MB scratch spills in r3/r4;
// even ",2" made the allocator squeeze to 64 VGPR and spill ~10 MB in r2.
__global__ __launch_bounds__(BLOCK, 1)
void det_main(const float* __restrict__ v,
              const float* __restrict__ gt,
              const float* __restrict__ rois,
              const float* __restrict__ labels,
              const float* __restrict__ pre_score,
              const float* __restrict__ cls_w,
              const float* __restrict__ cls_b,
              const float* __restrict__ reg_w,
              const float* __restrict__ reg_b,
              float* __restrict__ partials)   // [BS][3]: cnum, cden, l1
{
    const int tid  = threadIdx.x;
    const int lane = tid & 63;
    const int wave = tid >> 6;
    const int l    = lane & 7;   // lane within group
    const int grp  = lane >> 3;  // group within wave (0..7)
    const int b    = blockIdx.x / BLOCKS_PER_BATCH;
    const int blk  = blockIdx.x % BLOCKS_PER_BATCH;
    const int p0   = blk * ROWS_PER_BLOCK + wave * ROWS_PER_WAVE + grp * RPG;

    __shared__ float s_w[8 * DIM];   // 16 KB: c=0..3 cls, c=4..7 reg
    __shared__ float s_gt[G * 4];
    __shared__ int   s_lab;
    __shared__ float s_red[WAVES][3];

    // ---- stage weights into LDS (flat float4 copy)
    {
        const float4* cw = (const float4*)cls_w;   // 512 float4
        const float4* rw = (const float4*)reg_w;   // 512 float4
        float4* sw = (float4*)s_w;
        #pragma unroll
        for (int i = 0; i < 2; ++i) sw[i * BLOCK + tid]       = cw[i * BLOCK + tid];
        #pragma unroll
        for (int i = 0; i < 2; ++i) sw[512 + i * BLOCK + tid] = rw[i * BLOCK + tid];
    }
    if (tid < G * 4) s_gt[tid] = gt[b * G * 4 + tid];
    if (tid == 0) {
        const float* lb = labels + b * 4;
        int li = 0; float lm = lb[0];
        #pragma unroll
        for (int i = 1; i < 4; ++i) if (lb[i] > lm) { lm = lb[i]; li = i; }
        s_lab = li;
    }
    __syncthreads();
    const int lab = s_lab;

    // ---- hoisted epilogue loads (latency hides under GEMV)
    float4 rbox = make_float4(0.f, 0.f, 0.f, 1.f);
    float ps = 0.0f;
    if (l < RPG) {
        const int p = p0 + l;
        rbox = *(const float4*)(rois + ((size_t)b * P + p) * 4);
        ps   = pre_score[((size_t)b * P + p) * 4 + lab];
    }

    const float cb0 = cls_b[0], cb1 = cls_b[1], cb2 = cls_b[2], cb3 = cls_b[3];
    const float rb0 = reg_b[0], rb1 = reg_b[1], rb2 = reg_b[2], rb3 = reg_b[3];

    // ---- GEMV: acc[c][r] = partial dot of row (p0+r) with matrix c
    float acc[8][RPG];
    #pragma unroll
    for (int c = 0; c < 8; ++c)
        #pragma unroll
        for (int r = 0; r < RPG; ++r) acc[c][r] = 0.0f;

    const float* vb = v + ((size_t)b * P + p0) * DIM + l * 4;

    // 2-deep double-buffered prefetch (safe: VGPR cap is 512, grid sets occ.)
    float4 nvA[RPG], nvB[RPG];
    #pragma unroll
    for (int r = 0; r < RPG; ++r) nvA[r] = *(const float4*)(vb + r * DIM);
    #pragma unroll
    for (int r = 0; r < RPG; ++r) nvB[r] = *(const float4*)(vb + r * DIM + 32);

    #pragma unroll 2
    for (int k = 0; k < KSTEPS; k += 2) {
        // ---- step k: consume nvA
        {
            float4 wv[8];
            #pragma unroll
            for (int c = 0; c < 8; ++c)
                wv[c] = *(const float4*)&s_w[c * DIM + l * 4 + k * 32];
            #pragma unroll
            for (int c = 0; c < 8; ++c)
                #pragma unroll
                for (int r = 0; r < RPG; ++r)
                    acc[c][r] += wv[c].x * nvA[r].x + wv[c].y * nvA[r].y
                               + wv[c].z * nvA[r].z + wv[c].w * nvA[r].w;
            if (k + 2 < KSTEPS) {
                #pragma unroll
                for (int r = 0; r < RPG; ++r)
                    nvA[r] = *(const float4*)(vb + r * DIM + (k + 2) * 32);
            }
        }
        // ---- step k+1: consume nvB
        {
            float4 wv[8];
            #pragma unroll
            for (int c = 0; c < 8; ++c)
                wv[c] = *(const float4*)&s_w[c * DIM + l * 4 + (k + 1) * 32];
            #pragma unroll
            for (int c = 0; c < 8; ++c)
                #pragma unroll
                for (int r = 0; r < RPG; ++r)
                    acc[c][r] += wv[c].x * nvB[r].x + wv[c].y * nvB[r].y
                               + wv[c].z * nvB[r].z + wv[c].w * nvB[r].w;
            if (k + 3 < KSTEPS) {
                #pragma unroll
                for (int r = 0; r < RPG; ++r)
                    nvB[r] = *(const float4*)(vb + r * DIM + (k + 3) * 32);
            }
        }
    }

    // ---- reduce across the 8 lanes of each group (3 butterfly steps)
    #pragma unroll
    for (int c = 0; c < 8; ++c)
        #pragma unroll
        for (int r = 0; r < RPG; ++r) {
            float x = acc[c][r];
            x += __shfl_xor(x, 1);
            x += __shfl_xor(x, 2);
            x += __shfl_xor(x, 4);
            acc[c][r] = x;
        }

    // ---- epilogue: lane l (<RPG) of each group handles row p0+l
    float acc_cnum = 0.0f, acc_cden = 0.0f, acc_l1 = 0.0f;
    if (l < RPG) {
        float d[8];
        #pragma unroll
        for (int r = 0; r < RPG; ++r)
            if (l == r) {
                #pragma unroll
                for (int c = 0; c < 8; ++c) d[c] = acc[c][r];
            }
        const float area_r = (rbox.z - rbox.x) * (rbox.w - rbox.y);

        float biou = -1.0f; int bidx = 0;
        #pragma unroll
        for (int gi = 0; gi < G; ++gi) {
            float g0 = s_gt[gi * 4 + 0], g1 = s_gt[gi * 4 + 1];
            float g2 = s_gt[gi * 4 + 2], g3 = s_gt[gi * 4 + 3];
            float ltx = fmaxf(g0, rbox.x), lty = fmaxf(g1, rbox.y);
            float rbx = fminf(g2, rbox.z), rby = fminf(g3, rbox.w);
            float wx = fmaxf(rbx - ltx, 0.0f), wy = fmaxf(rby - lty, 0.0f);
            float inter = wx * wy;
            float ag = (g2 - g0) * (g3 - g1);
            float iou = inter / (ag + area_r - inter);
            if (iou > biou) { biou = iou; bidx = gi; }
        }
        const float mask = biou > 0.5f ? 1.0f : 0.0f;

        // cross-entropy on clipped logits
        float c0 = fminf(fmaxf(d[0] + cb0, 1e-7f), 0.99999994f);
        float c1 = fminf(fmaxf(d[1] + cb1, 1e-7f), 0.99999994f);
        float c2 = fminf(fmaxf(d[2] + cb2, 1e-7f), 0.99999994f);
        float c3 = fminf(fmaxf(d[3] + cb3, 1e-7f), 0.99999994f);
        float m  = fmaxf(fmaxf(c0, c1), fmaxf(c2, c3));
        float s  = expf(c0 - m) + expf(c1 - m) + expf(c2 - m) + expf(c3 - m);
        float lse = m + logf(s);
        float csel = lab == 0 ? c0 : (lab == 1 ? c1 : (lab == 2 ? c2 : c3));
        float ce = lse - csel;

        acc_cnum = ce * ps * mask;
        acc_cden = mask;

        // regression loss vs best-GT targets
        float bg0 = s_gt[bidx * 4 + 0], bg1 = s_gt[bidx * 4 + 1];
        float bg2 = s_gt[bidx * 4 + 2], bg3 = s_gt[bidx * 4 + 3];
        float gx = (bg2 + bg0) * 0.5f, gy = (bg3 + bg1) * 0.5f;
        float gw = (bg2 - bg0) * 0.5f, gh = (bg3 - bg1) * 0.5f;
        float rx = (rbox.z + rbox.x) * 0.5f, ry = (rbox.w + rbox.y) * 0.5f;
        float rw_ = (rbox.z - rbox.x) * 0.5f, rh = (rbox.w - rbox.y) * 0.5f;
        float tx = (gx - rx) / (rw_ + 1e-8f);
        float ty = (gy - ry) / (rh + 1e-8f);
        float tw = logf(gw / (rw_ + 1e-8f));
        float th = logf(gh / (rh + 1e-8f));
        float l1v = smooth_l1(d[4] + rb0 - tx) + smooth_l1(d[5] + rb1 - ty)
                  + smooth_l1(d[6] + rb2 - tw) + smooth_l1(d[7] + rb3 - th);
        acc_l1 = l1v * mask * ps;
    }

    // ---- full-wave butterfly sum of the three partials
    #pragma unroll
    for (int off = 32; off > 0; off >>= 1) {
        acc_cnum += __shfl_xor(acc_cnum, off);
        acc_cden += __shfl_xor(acc_cden, off);
        acc_l1   += __shfl_xor(acc_l1,   off);
    }
    if (lane == 0) {
        s_red[wave][0] = acc_cnum;
        s_red[wave][1] = acc_cden;
        s_red[wave][2] = acc_l1;
    }
    __syncthreads();
    if (tid == 0) {
        float a = 0.0f, bb = 0.0f, cc = 0.0f;
        #pragma unroll
        for (int wv = 0; wv < WAVES; ++wv) {
            a  += s_red[wv][0];
            bb += s_red[wv][1];
            cc += s_red[wv][2];
        }
        atomicAdd(&partials[b * 3 + 0], a);
        atomicAdd(&partials[b * 3 + 1], bb);
        atomicAdd(&partials[b * 3 + 2], cc);
    }
}

__global__ void det_final(const float* __restrict__ partials, float* __restrict__ out)
{
    if (threadIdx.x == 0 && blockIdx.x == 0) {
        float cl = 0.0f, l1 = 0.0f;
        #pragma unroll
        for (int b = 0; b < BS; ++b) {
            cl += partials[b * 3 + 0] / (partials[b * 3 + 1] + 1e-7f);
            l1 += partials[b * 3 + 2];
        }
        out[0] = cl / ((float)BS + 1e-7f) + l1 / (float)(BS * P);
    }
}

extern "C" void kernel_launch(void* const* d_in, const int* in_sizes, int n_in,
                              void* d_out, int out_size, void* d_ws, size_t ws_size,
                              hipStream_t stream) {
    const float* v         = (const float*)d_in[0];
    const float* gt        = (const float*)d_in[1];
    const float* rois      = (const float*)d_in[2];
    const float* labels    = (const float*)d_in[3];
    const float* pre_score = (const float*)d_in[4];
    const float* cls_w     = (const float*)d_in[5];
    const float* cls_b     = (const float*)d_in[6];
    const float* reg_w     = (const float*)d_in[7];
    const float* reg_b     = (const float*)d_in[8];
    float* partials = (float*)d_ws;
    float* out      = (float*)d_out;

    hipMemsetAsync(d_ws, 0, BS * 3 * sizeof(float), stream);
    det_main<<<(BS * P) / ROWS_PER_BLOCK, BLOCK, 0, stream>>>(
        v, gt, rois, labels, pre_score, cls_w, cls_b, reg_w, reg_b, partials);
    det_final<<<1, 64, 0, stream>>>(partials, out);
}